// Round 5
// baseline (183.551 us; speedup 1.0000x reference)
//
#include <hip/hip_runtime.h>

#define SS 2048
#define DD 64
#define BH 32      // B*H
#define VS 40      // Ps leading stride in shorts (32 + 8 pad)
#define M_SUB 16.0f
#define QSCALE 0.1803368801f   // 0.125 * log2(e)
#define CH 16                  // kt-tiles (32 k each) per chunk
#define NCHUNK 160             // sum over sp of ceil((sp+1)/CH)
#define NSLOT (BH * NCHUNK)    // 5120 partial slots

typedef __attribute__((ext_vector_type(8))) short short8;
typedef __attribute__((ext_vector_type(4))) float floatx4;

__device__ __forceinline__ short f2bf(float x) {        // RNE (pre-pass)
  union { float f; unsigned u; } un; un.f = x;
  unsigned r = (un.u + 0x7FFFu + ((un.u >> 16) & 1u)) >> 16;
  return (short)r;
}
__device__ __forceinline__ short f2bf_fast(float x) {   // round, 2 VALU ops
  union { float f; unsigned u; } un; un.f = x;
  return (short)((un.u + 0x8000u) >> 16);
}
__device__ __forceinline__ float fexp2(float x) {
  return __builtin_amdgcn_exp2f(x);
}
#define MFMA __builtin_amdgcn_mfma_f32_16x16x32_bf16

// ---------- pre-pass 1: K fp32 -> bf16, same layout ----------
__global__ __launch_bounds__(256) void prep_k(const float* __restrict__ K,
                                              short* __restrict__ Kbf) {
  const size_t i = ((size_t)blockIdx.x * 256 + threadIdx.x) * 8;
  floatx4 a = *(const floatx4*)(K + i);
  floatx4 b = *(const floatx4*)(K + i + 4);
  short8 s;
  s[0]=f2bf(a[0]); s[1]=f2bf(a[1]); s[2]=f2bf(a[2]); s[3]=f2bf(a[3]);
  s[4]=f2bf(b[0]); s[5]=f2bf(b[1]); s[6]=f2bf(b[2]); s[7]=f2bf(b[3]);
  *(short8*)(Kbf + i) = s;
}

// ---------- pre-pass 2: V fp32 -> bf16 transposed [bh][d][s] ----------
__global__ __launch_bounds__(256) void prep_vt(const float* __restrict__ V,
                                               short* __restrict__ Vt) {
  __shared__ short Ts[64][72];
  const int bh = blockIdx.y;
  const int s0 = blockIdx.x * 64;
  const int t = threadIdx.x;
  {
    const int r = t >> 2, c = (t & 3) * 16;
    const float* g = V + ((size_t)bh * SS + s0 + r) * DD + c;
    floatx4 a = *(const floatx4*)g;
    floatx4 b = *(const floatx4*)(g + 4);
    floatx4 cc = *(const floatx4*)(g + 8);
    floatx4 d = *(const floatx4*)(g + 12);
    short8 x0, x1;
    x0[0]=f2bf(a[0]); x0[1]=f2bf(a[1]); x0[2]=f2bf(a[2]); x0[3]=f2bf(a[3]);
    x0[4]=f2bf(b[0]); x0[5]=f2bf(b[1]); x0[6]=f2bf(b[2]); x0[7]=f2bf(b[3]);
    x1[0]=f2bf(cc[0]);x1[1]=f2bf(cc[1]);x1[2]=f2bf(cc[2]);x1[3]=f2bf(cc[3]);
    x1[4]=f2bf(d[0]); x1[5]=f2bf(d[1]); x1[6]=f2bf(d[2]); x1[7]=f2bf(d[3]);
    *(short8*)&Ts[r][c] = x0;
    *(short8*)&Ts[r][c + 8] = x1;
  }
  __syncthreads();
  {
    const int d = t >> 2, sb = (t & 3) * 16;
    short8 y0, y1;
    #pragma unroll
    for (int j = 0; j < 8; ++j) { y0[j] = Ts[sb + j][d]; y1[j] = Ts[sb + 8 + j][d]; }
    short* o = Vt + ((size_t)bh * DD + d) * SS + s0 + sb;
    *(short8*)o = y0;
    *(short8*)(o + 8) = y1;
  }
}

// chunk id y in [0,160) -> (strip-pair sp, chunk index c)
__device__ __forceinline__ void y2spc(int y, int& sp, int& c) {
  if (y < 16)      { sp = y;                              c = 0; }
  else if (y < 48) { int i = y - 16; sp = 16 + (i >> 1);  c = i & 1; }
  else if (y < 96) { int i = y - 48; sp = 32 + i / 3;     c = i - (sp - 32) * 3; }
  else             { int i = y - 96; sp = 48 + (i >> 2);  c = i & 3; }
}

// ---------- main: split-K partial attention, 1 wave, 32 q-rows, <=16 kt ----------
__global__ __launch_bounds__(64) void sdpa_part(
    const float* __restrict__ Q, const short* __restrict__ Kbf,
    const short* __restrict__ Vt, float* __restrict__ PO,
    float* __restrict__ PRS) {
  __shared__ __align__(16) short Ps[2][16 * VS];

  const int lane = threadIdx.x & 63;
  const int quad = lane >> 4;
  const int l16  = lane & 15;

  const int bh = blockIdx.x;           // x = bh -> XCD id%8 = bh%8 (L2 local)
  const int y  = blockIdx.y;
  int sp, c; y2spc(y, sp, c);
  const int qA = sp * 32;
  const int qB = qA + 16;
  const int kt0 = c * CH;
  const int kt1 = min(kt0 + CH, sp + 1);

  const size_t base = (size_t)bh * SS * DD;

  // ---- Q fragments for both strips ----
  short8 qaA0, qaA1, qaB0, qaB1;
  {
    const float* ga = Q + base + (size_t)(qA + l16) * DD + quad * 8;
    const float* gb = Q + base + (size_t)(qB + l16) * DD + quad * 8;
    floatx4 a0 = *(const floatx4*)ga,        a1 = *(const floatx4*)(ga + 4);
    floatx4 a2 = *(const floatx4*)(ga + 32), a3 = *(const floatx4*)(ga + 36);
    floatx4 b0 = *(const floatx4*)gb,        b1 = *(const floatx4*)(gb + 4);
    floatx4 b2 = *(const floatx4*)(gb + 32), b3 = *(const floatx4*)(gb + 36);
    #pragma unroll
    for (int j = 0; j < 4; ++j) {
      qaA0[j] = f2bf(a0[j] * QSCALE); qaA0[4 + j] = f2bf(a1[j] * QSCALE);
      qaA1[j] = f2bf(a2[j] * QSCALE); qaA1[4 + j] = f2bf(a3[j] * QSCALE);
      qaB0[j] = f2bf(b0[j] * QSCALE); qaB0[4 + j] = f2bf(b1[j] * QSCALE);
      qaB1[j] = f2bf(b2[j] * QSCALE); qaB1[4 + j] = f2bf(b3[j] * QSCALE);
    }
  }

  floatx4 z = {0.f, 0.f, 0.f, 0.f};
  floatx4 oA0 = z, oA1 = z, oA2 = z, oA3 = z;
  floatx4 oB0 = z, oB1 = z, oB2 = z, oB3 = z;
  float rsA[4] = {0.f,0.f,0.f,0.f}, rsB[4] = {0.f,0.f,0.f,0.f};

  const short* kbase = Kbf + base;
  const short* vbase = Vt + (size_t)bh * DD * SS;
  const int koffL = l16 * DD + quad * 8;
  const int koffH = (16 + l16) * DD + quad * 8;

  // prefetch first K tile
  const short* kr0 = kbase + (size_t)kt0 * 32 * DD;
  short8 kb00 = *(const short8*)(kr0 + koffL);
  short8 kb01 = *(const short8*)(kr0 + koffL + 32);
  short8 kb10 = *(const short8*)(kr0 + koffH);
  short8 kb11 = *(const short8*)(kr0 + koffH + 32);

  for (int kt = kt0; kt < kt1; ++kt) {
    const int k0 = kt * 32;

    floatx4 sA0 = z, sA1 = z, sB0 = z, sB1 = z;
    sA0 = MFMA(qaA0, kb00, sA0, 0, 0, 0); sA0 = MFMA(qaA1, kb01, sA0, 0, 0, 0);
    sA1 = MFMA(qaA0, kb10, sA1, 0, 0, 0); sA1 = MFMA(qaA1, kb11, sA1, 0, 0, 0);
    sB0 = MFMA(qaB0, kb00, sB0, 0, 0, 0); sB0 = MFMA(qaB1, kb01, sB0, 0, 0, 0);
    sB1 = MFMA(qaB0, kb10, sB1, 0, 0, 0); sB1 = MFMA(qaB1, kb11, sB1, 0, 0, 0);

    // V loads issued early
    const short* vr = vbase + k0 + quad * 8;
    short8 vb0 = *(const short8*)(vr + (size_t)(l16)      * SS);
    short8 vb1 = *(const short8*)(vr + (size_t)(16 + l16) * SS);
    short8 vb2 = *(const short8*)(vr + (size_t)(32 + l16) * SS);
    short8 vb3 = *(const short8*)(vr + (size_t)(48 + l16) * SS);

    // next K prefetch issued early
    const short* krn = kbase + (size_t)((kt + 1 < kt1) ? k0 + 32 : k0) * DD;
    short8 nk00 = *(const short8*)(krn + koffL);
    short8 nk01 = *(const short8*)(krn + koffL + 32);
    short8 nk10 = *(const short8*)(krn + koffH);
    short8 nk11 = *(const short8*)(krn + koffH + 32);

    if (kt == sp) {   // diagonal tile (only in a strip's last chunk)
      const int kgl = k0 + l16, kgh = k0 + 16 + l16;
      #pragma unroll
      for (int r = 0; r < 4; ++r) {
        const int ra = qA + quad * 4 + r, rb = qB + quad * 4 + r;
        sA0[r] = (kgl <= ra) ? sA0[r] : -1e30f;
        sA1[r] = (kgh <= ra) ? sA1[r] : -1e30f;
        sB0[r] = (kgl <= rb) ? sB0[r] : -1e30f;
        sB1[r] = (kgh <= rb) ? sB1[r] : -1e30f;
      }
    }

    #pragma unroll
    for (int r = 0; r < 4; ++r) {
      const float pA0 = fexp2(sA0[r] - M_SUB), pA1 = fexp2(sA1[r] - M_SUB);
      const float pB0 = fexp2(sB0[r] - M_SUB), pB1 = fexp2(sB1[r] - M_SUB);
      rsA[r] += pA0 + pA1;
      rsB[r] += pB0 + pB1;
      const int ro = (quad * 4 + r) * VS;
      Ps[0][ro + l16]      = f2bf_fast(pA0);
      Ps[0][ro + 16 + l16] = f2bf_fast(pA1);
      Ps[1][ro + l16]      = f2bf_fast(pB0);
      Ps[1][ro + 16 + l16] = f2bf_fast(pB1);
    }
    __asm__ volatile("s_waitcnt lgkmcnt(0)" ::: "memory");
    const short8 paA = *(const short8*)&Ps[0][l16 * VS + quad * 8];
    const short8 paB = *(const short8*)&Ps[1][l16 * VS + quad * 8];

    oA0 = MFMA(paA, vb0, oA0, 0, 0, 0); oA1 = MFMA(paA, vb1, oA1, 0, 0, 0);
    oA2 = MFMA(paA, vb2, oA2, 0, 0, 0); oA3 = MFMA(paA, vb3, oA3, 0, 0, 0);
    oB0 = MFMA(paB, vb0, oB0, 0, 0, 0); oB1 = MFMA(paB, vb1, oB1, 0, 0, 0);
    oB2 = MFMA(paB, vb2, oB2, 0, 0, 0); oB3 = MFMA(paB, vb3, oB3, 0, 0, 0);

    kb00 = nk00; kb01 = nk01; kb10 = nk10; kb11 = nk11;
  }

  // ---- row sums across the 16 lanes of each quad-row ----
  #pragma unroll
  for (int off = 1; off < 16; off <<= 1) {
    #pragma unroll
    for (int r = 0; r < 4; ++r) {
      rsA[r] += __shfl_xor(rsA[r], off, 64);
      rsB[r] += __shfl_xor(rsB[r], off, 64);
    }
  }

  // ---- store unnormalized partials ----
  const int slot = bh * NCHUNK + y;
  float* po = PO + (size_t)slot * (32 * 64);
  #pragma unroll
  for (int r = 0; r < 4; ++r) {
    float* rowA = po + (quad * 4 + r) * 64;
    float* rowB = po + (16 + quad * 4 + r) * 64;
    rowA[l16]      = oA0[r];
    rowA[16 + l16] = oA1[r];
    rowA[32 + l16] = oA2[r];
    rowA[48 + l16] = oA3[r];
    rowB[l16]      = oB0[r];
    rowB[16 + l16] = oB1[r];
    rowB[32 + l16] = oB2[r];
    rowB[48 + l16] = oB3[r];
  }
  if (l16 == 0) {
    float* prs = PRS + slot * 32;
    #pragma unroll
    for (int r = 0; r < 4; ++r) {
      prs[quad * 4 + r]      = rsA[r];
      prs[16 + quad * 4 + r] = rsB[r];
    }
  }
}

// ---------- combine: sum partials, normalize, write O ----------
__global__ __launch_bounds__(256) void sdpa_combine(
    const float* __restrict__ PO, const float* __restrict__ PRS,
    float* __restrict__ O) {
  const int bh = blockIdx.x;
  const int sp = blockIdx.y;
  const int t  = threadIdx.x;
  const int row = t >> 3;          // 0..31
  const int col = (t & 7) * 8;     // 0..56

  const int g  = sp >> 4;
  const int cn = g + 1;                          // chunks for this strip-pair
  const int ybase = 8 * g * (g + 1) + (sp - g * 16) * cn;

  floatx4 accL = {0.f,0.f,0.f,0.f}, accH = accL;
  float den = 0.f;
  for (int c = 0; c < cn; ++c) {
    const int slot = bh * NCHUNK + ybase + c;
    const float* po = PO + (size_t)slot * (32 * 64) + row * 64 + col;
    floatx4 a = *(const floatx4*)po;
    floatx4 b = *(const floatx4*)(po + 4);
    accL += a; accH += b;
    den += PRS[slot * 32 + row];
  }
  const float inv = 1.0f / den;
  accL *= inv; accH *= inv;
  float* out = O + ((size_t)bh * SS + sp * 32 + row) * DD + col;
  *(floatx4*)out = accL;
  *(floatx4*)(out + 4) = accH;
}

extern "C" void kernel_launch(void* const* d_in, const int* in_sizes, int n_in,
                              void* d_out, int out_size, void* d_ws, size_t ws_size,
                              hipStream_t stream) {
  (void)in_sizes; (void)n_in; (void)out_size; (void)ws_size;
  const float* q = (const float*)d_in[0];
  const float* k = (const float*)d_in[1];
  const float* v = (const float*)d_in[2];
  float* o = (float*)d_out;

  short* Kbf = (short*)d_ws;                               // 8 MB
  short* Vt  = Kbf + (size_t)BH * SS * DD;                 // 8 MB
  float* PO  = (float*)(Vt + (size_t)BH * SS * DD);        // 40 MB
  float* PRS = PO + (size_t)NSLOT * 32 * 64;               // 640 KB

  prep_k<<<dim3(BH * SS * DD / 8 / 256), 256, 0, stream>>>(k, Kbf);
  prep_vt<<<dim3(SS / 64, BH), 256, 0, stream>>>(v, Vt);
  sdpa_part<<<dim3(BH, NCHUNK), 64, 0, stream>>>(q, Kbf, Vt, PO, PRS);
  sdpa_combine<<<dim3(BH, SS / 32), 256, 0, stream>>>(PO, PRS, o);
}

// Round 6
// 183.247 us; speedup vs baseline: 1.0017x; 1.0017x over previous
//
#include <hip/hip_runtime.h>

#define SS 2048
#define DD 64
#define BH 32      // B*H
#define M_SUB 16.0f
#define QSCALE 0.1803368801f   // 0.125 * log2(e)
#define CH 16                  // kt-tiles (32 k each) per chunk
#define NCHUNK 160             // sum over sp of ceil((sp+1)/CH)
#define NSLOT (BH * NCHUNK)    // 5120 partial slots

typedef __attribute__((ext_vector_type(8))) short short8;
typedef __attribute__((ext_vector_type(4))) float floatx4;

__device__ __forceinline__ short f2bf(float x) {        // RNE (pre-pass)
  union { float f; unsigned u; } un; un.f = x;
  unsigned r = (un.u + 0x7FFFu + ((un.u >> 16) & 1u)) >> 16;
  return (short)r;
}
__device__ __forceinline__ short f2bf_fast(float x) {   // round-to-nearest, 2 ops
  union { float f; unsigned u; } un; un.f = x;
  return (short)((un.u + 0x8000u) >> 16);
}
__device__ __forceinline__ float fexp2(float x) {
  return __builtin_amdgcn_exp2f(x);
}
#define MFMA __builtin_amdgcn_mfma_f32_16x16x32_bf16

// ---------- pre-pass 1: K fp32 -> bf16, same layout ----------
__global__ __launch_bounds__(256) void prep_k(const float* __restrict__ K,
                                              short* __restrict__ Kbf) {
  const size_t i = ((size_t)blockIdx.x * 256 + threadIdx.x) * 8;
  floatx4 a = *(const floatx4*)(K + i);
  floatx4 b = *(const floatx4*)(K + i + 4);
  short8 s;
  s[0]=f2bf(a[0]); s[1]=f2bf(a[1]); s[2]=f2bf(a[2]); s[3]=f2bf(a[3]);
  s[4]=f2bf(b[0]); s[5]=f2bf(b[1]); s[6]=f2bf(b[2]); s[7]=f2bf(b[3]);
  *(short8*)(Kbf + i) = s;
}

// slot c (0..31) -> physical k within 32-tile: quad=c>>3, h=(c>>2)&1, r=c&3
__device__ __forceinline__ int kperm(int c) {
  return (((c >> 2) & 1) << 4) + ((c >> 3) << 2) + (c & 3);
}

// ---------- pre-pass 2: V fp32 -> bf16, transposed [bh][d][k] with k-slot perm ----------
__global__ __launch_bounds__(256) void prep_vtp(const float* __restrict__ V,
                                                short* __restrict__ Vtp) {
  __shared__ short Ts[64][72];
  const int bh = blockIdx.y;
  const int s0 = blockIdx.x * 64;
  const int t = threadIdx.x;
  {
    const int r = t >> 2, c = (t & 3) * 16;
    const float* g = V + ((size_t)bh * SS + s0 + r) * DD + c;
    floatx4 a = *(const floatx4*)g;
    floatx4 b = *(const floatx4*)(g + 4);
    floatx4 cc = *(const floatx4*)(g + 8);
    floatx4 d = *(const floatx4*)(g + 12);
    short8 x0, x1;
    x0[0]=f2bf(a[0]); x0[1]=f2bf(a[1]); x0[2]=f2bf(a[2]); x0[3]=f2bf(a[3]);
    x0[4]=f2bf(b[0]); x0[5]=f2bf(b[1]); x0[6]=f2bf(b[2]); x0[7]=f2bf(b[3]);
    x1[0]=f2bf(cc[0]);x1[1]=f2bf(cc[1]);x1[2]=f2bf(cc[2]);x1[3]=f2bf(cc[3]);
    x1[4]=f2bf(d[0]); x1[5]=f2bf(d[1]); x1[6]=f2bf(d[2]); x1[7]=f2bf(d[3]);
    *(short8*)&Ts[r][c] = x0;
    *(short8*)&Ts[r][c + 8] = x1;
  }
  __syncthreads();
  {
    const int d = t >> 2, cblk = (t & 3) * 16;
    short8 y0, y1;
    #pragma unroll
    for (int j = 0; j < 8; ++j) {
      const int c0 = cblk + j, c1 = cblk + 8 + j;
      y0[j] = Ts[(c0 & 32) + kperm(c0 & 31)][d];
      y1[j] = Ts[(c1 & 32) + kperm(c1 & 31)][d];
    }
    short* o = Vtp + ((size_t)bh * DD + d) * SS + s0 + cblk;
    *(short8*)o = y0;
    *(short8*)(o + 8) = y1;
  }
}

// chunk id y in [0,160) -> (strip-pair sp, chunk index c)
__device__ __forceinline__ void y2spc(int y, int& sp, int& c) {
  if (y < 16)      { sp = y;                              c = 0; }
  else if (y < 48) { int i = y - 16; sp = 16 + (i >> 1);  c = i & 1; }
  else if (y < 96) { int i = y - 48; sp = 32 + i / 3;     c = i - (sp - 32) * 3; }
  else             { int i = y - 96; sp = 48 + (i >> 2);  c = i & 3; }
}

// ---------- main: split-K partials, S^T trick, zero LDS, 1 wave ----------
__global__ __launch_bounds__(64, 4) void sdpa_part(
    const float* __restrict__ Q, const short* __restrict__ Kbf,
    const short* __restrict__ Vtp, float* __restrict__ PO,
    float* __restrict__ PRS) {
  const int lane = threadIdx.x & 63;
  const int quad = lane >> 4;
  const int l16  = lane & 15;

  const int bh = blockIdx.x;           // x = bh -> XCD id%8 = bh%8 (L2 local)
  const int y  = blockIdx.y;
  int sp, c; y2spc(y, sp, c);
  const int qA = sp * 32;
  const int qB = qA + 16;
  const int kt0 = c * CH;
  const int kt1 = min(kt0 + CH, sp + 1);

  const size_t base = (size_t)bh * SS * DD;

  // ---- Q fragments (B-operand layout: lane holds Q[q=l16][d=quad*8+j]) ----
  short8 qaA0, qaA1, qaB0, qaB1;
  {
    const float* ga = Q + base + (size_t)(qA + l16) * DD + quad * 8;
    const float* gb = Q + base + (size_t)(qB + l16) * DD + quad * 8;
    floatx4 a0 = *(const floatx4*)ga,        a1 = *(const floatx4*)(ga + 4);
    floatx4 a2 = *(const floatx4*)(ga + 32), a3 = *(const floatx4*)(ga + 36);
    floatx4 b0 = *(const floatx4*)gb,        b1 = *(const floatx4*)(gb + 4);
    floatx4 b2 = *(const floatx4*)(gb + 32), b3 = *(const floatx4*)(gb + 36);
    #pragma unroll
    for (int j = 0; j < 4; ++j) {
      qaA0[j] = f2bf(a0[j] * QSCALE); qaA0[4 + j] = f2bf(a1[j] * QSCALE);
      qaA1[j] = f2bf(a2[j] * QSCALE); qaA1[4 + j] = f2bf(a3[j] * QSCALE);
      qaB0[j] = f2bf(b0[j] * QSCALE); qaB0[4 + j] = f2bf(b1[j] * QSCALE);
      qaB1[j] = f2bf(b2[j] * QSCALE); qaB1[4 + j] = f2bf(b3[j] * QSCALE);
    }
  }

  floatx4 z = {0.f, 0.f, 0.f, 0.f};
  floatx4 oA0 = z, oA1 = z, oA2 = z, oA3 = z;   // O^T tiles: d = t*16+quad*4+r, q = l16
  floatx4 oB0 = z, oB1 = z, oB2 = z, oB3 = z;
  float rsA = 0.f, rsB = 0.f;                   // per-lane partial row sums (q = l16)

  const short* kbase = Kbf + base;
  const short* vbase = Vtp + (size_t)bh * DD * SS;
  const int koffL = l16 * DD + quad * 8;
  const int koffH = (16 + l16) * DD + quad * 8;

  // prefetch first K tile
  const short* kr0 = kbase + (size_t)kt0 * 32 * DD;
  short8 kb00 = *(const short8*)(kr0 + koffL);
  short8 kb01 = *(const short8*)(kr0 + koffL + 32);
  short8 kb10 = *(const short8*)(kr0 + koffH);
  short8 kb11 = *(const short8*)(kr0 + koffH + 32);

  for (int kt = kt0; kt < kt1; ++kt) {
    const int k0 = kt * 32;

    // ---- issue V (this tile) and next-K loads first ----
    const short* vr = vbase + k0 + quad * 8;
    short8 vt0 = *(const short8*)(vr + (size_t)(l16)      * SS);
    short8 vt1 = *(const short8*)(vr + (size_t)(16 + l16) * SS);
    short8 vt2 = *(const short8*)(vr + (size_t)(32 + l16) * SS);
    short8 vt3 = *(const short8*)(vr + (size_t)(48 + l16) * SS);
    const short* krn = kbase + (size_t)((kt + 1 < kt1) ? k0 + 32 : k0) * DD;
    short8 nk00 = *(const short8*)(krn + koffL);
    short8 nk01 = *(const short8*)(krn + koffL + 32);
    short8 nk10 = *(const short8*)(krn + koffH);
    short8 nk11 = *(const short8*)(krn + koffH + 32);

    // ---- S^T = K Q^T : C-layout row = k (quad*4+r), col = q (l16) ----
    floatx4 tA0 = z, tA1 = z, tB0 = z, tB1 = z;
    tA0 = MFMA(kb00, qaA0, tA0, 0, 0, 0); tA0 = MFMA(kb01, qaA1, tA0, 0, 0, 0);
    tA1 = MFMA(kb10, qaA0, tA1, 0, 0, 0); tA1 = MFMA(kb11, qaA1, tA1, 0, 0, 0);
    tB0 = MFMA(kb00, qaB0, tB0, 0, 0, 0); tB0 = MFMA(kb01, qaB1, tB0, 0, 0, 0);
    tB1 = MFMA(kb10, qaB0, tB1, 0, 0, 0); tB1 = MFMA(kb11, qaB1, tB1, 0, 0, 0);

    // ---- causal mask on the diagonal tile only ----
    if (kt == sp) {
      const int kq = quad * 4;         // local k = kq + r  (tA1: +16)
      #pragma unroll
      for (int r = 0; r < 4; ++r) {
        tA0[r] = (kq + r      <= l16) ? tA0[r] : -1e30f;
        tA1[r] = (kq + r + 16 <= l16) ? tA1[r] : -1e30f;
        tB0[r] = (kq + r      <= l16 + 16) ? tB0[r] : -1e30f;
        tB1[r] = (kq + r      <= l16)      ? tB1[r] : -1e30f;  // +16 both sides
      }
    }

    // ---- exp2, pack P directly into B-operand fragments (no LDS!) ----
    short8 paA, paB;
    #pragma unroll
    for (int r = 0; r < 4; ++r) {
      const float pA0 = fexp2(tA0[r] - M_SUB), pA1 = fexp2(tA1[r] - M_SUB);
      const float pB0 = fexp2(tB0[r] - M_SUB), pB1 = fexp2(tB1[r] - M_SUB);
      rsA += pA0 + pA1;
      rsB += pB0 + pB1;
      paA[r] = f2bf_fast(pA0); paA[4 + r] = f2bf_fast(pA1);
      paB[r] = f2bf_fast(pB0); paB[4 + r] = f2bf_fast(pB1);
    }

    // ---- O^T += V^T P^T  (Vtp pre-permuted to match P's k-slot order) ----
    oA0 = MFMA(vt0, paA, oA0, 0, 0, 0); oA1 = MFMA(vt1, paA, oA1, 0, 0, 0);
    oA2 = MFMA(vt2, paA, oA2, 0, 0, 0); oA3 = MFMA(vt3, paA, oA3, 0, 0, 0);
    oB0 = MFMA(vt0, paB, oB0, 0, 0, 0); oB1 = MFMA(vt1, paB, oB1, 0, 0, 0);
    oB2 = MFMA(vt2, paB, oB2, 0, 0, 0); oB3 = MFMA(vt3, paB, oB3, 0, 0, 0);

    kb00 = nk00; kb01 = nk01; kb10 = nk10; kb11 = nk11;
  }

  // ---- row sums: reduce across quads (k-coverage), q = l16 fixed ----
  rsA += __shfl_xor(rsA, 16, 64); rsA += __shfl_xor(rsA, 32, 64);
  rsB += __shfl_xor(rsB, 16, 64); rsB += __shfl_xor(rsB, 32, 64);

  // ---- store unnormalized partials: PO[slot][row 0..31][d 0..63] ----
  const int slot = bh * NCHUNK + y;
  float* po = PO + (size_t)slot * (32 * 64);
  float* ra = po + l16 * 64 + quad * 4;
  float* rb = po + (16 + l16) * 64 + quad * 4;
  *(floatx4*)(ra)      = oA0;
  *(floatx4*)(ra + 16) = oA1;
  *(floatx4*)(ra + 32) = oA2;
  *(floatx4*)(ra + 48) = oA3;
  *(floatx4*)(rb)      = oB0;
  *(floatx4*)(rb + 16) = oB1;
  *(floatx4*)(rb + 32) = oB2;
  *(floatx4*)(rb + 48) = oB3;
  if (quad == 0) {
    PRS[slot * 32 + l16]      = rsA;
    PRS[slot * 32 + 16 + l16] = rsB;
  }
}

// ---------- combine: sum partials, normalize, write O ----------
__global__ __launch_bounds__(256) void sdpa_combine(
    const float* __restrict__ PO, const float* __restrict__ PRS,
    float* __restrict__ O) {
  const int bh = blockIdx.x;
  const int sp = blockIdx.y;
  const int t  = threadIdx.x;
  const int row = t >> 3;          // 0..31
  const int col = (t & 7) * 8;     // 0..56

  const int g  = sp >> 4;
  const int cn = g + 1;                          // chunks for this strip-pair
  const int ybase = 8 * g * (g + 1) + (sp - g * 16) * cn;

  floatx4 accL = {0.f,0.f,0.f,0.f}, accH = accL;
  float den = 0.f;
  for (int c = 0; c < cn; ++c) {
    const int slot = bh * NCHUNK + ybase + c;
    const float* po = PO + (size_t)slot * (32 * 64) + row * 64 + col;
    floatx4 a = *(const floatx4*)po;
    floatx4 b = *(const floatx4*)(po + 4);
    accL += a; accH += b;
    den += PRS[slot * 32 + row];
  }
  const float inv = 1.0f / den;
  accL *= inv; accH *= inv;
  float* out = O + ((size_t)bh * SS + sp * 32 + row) * DD + col;
  *(floatx4*)out = accL;
  *(floatx4*)(out + 4) = accH;
}

extern "C" void kernel_launch(void* const* d_in, const int* in_sizes, int n_in,
                              void* d_out, int out_size, void* d_ws, size_t ws_size,
                              hipStream_t stream) {
  (void)in_sizes; (void)n_in; (void)out_size; (void)ws_size;
  const float* q = (const float*)d_in[0];
  const float* k = (const float*)d_in[1];
  const float* v = (const float*)d_in[2];
  float* o = (float*)d_out;

  short* Kbf = (short*)d_ws;                               // 8 MB
  short* Vtp = Kbf + (size_t)BH * SS * DD;                 // 8 MB
  float* PO  = (float*)(Vtp + (size_t)BH * SS * DD);       // 40 MB
  float* PRS = PO + (size_t)NSLOT * 32 * 64;               // 640 KB

  prep_k<<<dim3(BH * SS * DD / 8 / 256), 256, 0, stream>>>(k, Kbf);
  prep_vtp<<<dim3(SS / 64, BH), 256, 0, stream>>>(v, Vtp);
  sdpa_part<<<dim3(BH, NCHUNK), 64, 0, stream>>>(q, Kbf, Vtp, PO, PRS);
  sdpa_combine<<<dim3(BH, SS / 32), 256, 0, stream>>>(PO, PRS, o);
}

// Round 7
// 143.511 us; speedup vs baseline: 1.2790x; 1.2769x over previous
//
#include <hip/hip_runtime.h>

#define SS 2048
#define DD 64
#define BH 32      // B*H
#define M_SUB 16.0f
#define QSCALE 0.1803368801f   // 0.125 * log2(e)
#define NCHUNK 40              // chunks per bh: sum over 16 q-tiles of ceil((4qt+4)/16)
#define NSLOT (BH * NCHUNK)    // 1280 partial slots (128 rows each)

typedef __attribute__((ext_vector_type(8))) short short8;
typedef __attribute__((ext_vector_type(4))) float floatx4;

__device__ __forceinline__ short f2bf(float x) {        // RNE
  union { float f; unsigned u; } un; un.f = x;
  unsigned r = (un.u + 0x7FFFu + ((un.u >> 16) & 1u)) >> 16;
  return (short)r;
}
__device__ __forceinline__ short f2bf_fast(float x) {   // round-to-nearest, 2 ops
  union { float f; unsigned u; } un; un.f = x;
  return (short)((un.u + 0x8000u) >> 16);
}
__device__ __forceinline__ float fexp2(float x) {
  return __builtin_amdgcn_exp2f(x);
}
__device__ __forceinline__ void gload16(const short* g, short* l) {
  __builtin_amdgcn_global_load_lds(
      (const __attribute__((address_space(1))) void*)g,
      (__attribute__((address_space(3))) void*)l, 16, 0, 0);
}
#define MFMA __builtin_amdgcn_mfma_f32_16x16x32_bf16

// ---------- pre-pass 1: K fp32 -> bf16, same [bh][k][d] layout ----------
__global__ __launch_bounds__(256) void prep_k(const float* __restrict__ K,
                                              short* __restrict__ Kbf) {
  const size_t i = ((size_t)blockIdx.x * 256 + threadIdx.x) * 8;
  floatx4 a = *(const floatx4*)(K + i);
  floatx4 b = *(const floatx4*)(K + i + 4);
  short8 s;
  s[0]=f2bf(a[0]); s[1]=f2bf(a[1]); s[2]=f2bf(a[2]); s[3]=f2bf(a[3]);
  s[4]=f2bf(b[0]); s[5]=f2bf(b[1]); s[6]=f2bf(b[2]); s[7]=f2bf(b[3]);
  *(short8*)(Kbf + i) = s;
}

// slot c (0..31) -> physical k within 32-tile: quad=c>>3, h=(c>>2)&1, r=c&3
__device__ __forceinline__ int kperm(int c) {
  return (((c >> 2) & 1) << 4) + ((c >> 3) << 2) + (c & 3);
}

// ---------- pre-pass 2: V fp32 -> bf16, TILE-MAJOR [bh][tile][d][32], k-permuted ----------
__global__ __launch_bounds__(256) void prep_vtp(const float* __restrict__ V,
                                                short* __restrict__ Vtp) {
  __shared__ short Ts[64][72];
  const int bh = blockIdx.y;
  const int s0 = blockIdx.x * 64;
  const int t = threadIdx.x;
  {
    const int r = t >> 2, c = (t & 3) * 16;
    const float* g = V + ((size_t)bh * SS + s0 + r) * DD + c;
    floatx4 a = *(const floatx4*)g;
    floatx4 b = *(const floatx4*)(g + 4);
    floatx4 cc = *(const floatx4*)(g + 8);
    floatx4 d = *(const floatx4*)(g + 12);
    short8 x0, x1;
    x0[0]=f2bf(a[0]); x0[1]=f2bf(a[1]); x0[2]=f2bf(a[2]); x0[3]=f2bf(a[3]);
    x0[4]=f2bf(b[0]); x0[5]=f2bf(b[1]); x0[6]=f2bf(b[2]); x0[7]=f2bf(b[3]);
    x1[0]=f2bf(cc[0]);x1[1]=f2bf(cc[1]);x1[2]=f2bf(cc[2]);x1[3]=f2bf(cc[3]);
    x1[4]=f2bf(d[0]); x1[5]=f2bf(d[1]); x1[6]=f2bf(d[2]); x1[7]=f2bf(d[3]);
    *(short8*)&Ts[r][c] = x0;
    *(short8*)&Ts[r][c + 8] = x1;
  }
  __syncthreads();
  {
    const int d = t >> 2, cblk = (t & 3) * 16;
    short8 y0, y1;
    #pragma unroll
    for (int j = 0; j < 8; ++j) {
      const int c0 = cblk + j, c1 = cblk + 8 + j;
      y0[j] = Ts[(c0 & 32) + kperm(c0 & 31)][d];
      y1[j] = Ts[(c1 & 32) + kperm(c1 & 31)][d];
    }
    const int kt  = (s0 + cblk) >> 5;
    const int kin = cblk & 31;           // 0 or 16
    short* o = Vtp + (((size_t)bh * 64 + kt) * 64 + d) * 32 + kin;
    *(short8*)o = y0;
    *(short8*)(o + 8) = y1;
  }
}

// chunk id y in [0,40) -> (q-tile qt, chunk index c)
__device__ __forceinline__ void y2qc(int y, int& qt, int& c) {
  if (y < 4)       { qt = y;                            c = 0; }
  else if (y < 12) { int i = y - 4;  qt = 4 + (i >> 1); c = i & 1; }
  else if (y < 24) { int i = y - 12; qt = 8 + i / 3;    c = i - (qt - 8) * 3; }
  else             { int i = y - 24; qt = 12 + (i >> 2); c = i & 3; }
}

// ---------- main: 4 waves, 128 q-rows, LDS double-buffered coalesced staging ----------
__global__ __launch_bounds__(256, 4) void sdpa_part(
    const float* __restrict__ Q, const short* __restrict__ Kbf,
    const short* __restrict__ Vtp, float* __restrict__ PO,
    float* __restrict__ PRS) {
  // per buffer: K = 4 chunks x (512 shorts + 32 pad) = 2176, V = 4 x 512 = 2048
  __shared__ __align__(16) short Sh[2][4224];

  const int tid  = threadIdx.x;
  const int w    = tid >> 6;
  const int lane = tid & 63;
  const int quad = lane >> 4;
  const int l16  = lane & 15;

  const int bh = blockIdx.x;              // x = bh -> XCD id%8 = bh%8 (L2 local)
  const int y  = 39 - (int)blockIdx.y;    // big q-tiles dispatch first
  int qt, c; y2qc(y, qt, c);
  const int kt0 = c * 16;
  const int kt1 = min(kt0 + 16, 4 * qt + 4);
  const int ktd = 4 * qt + w;             // this wave's diagonal k-tile
  const int qA  = qt * 128 + w * 32;      // strip A rows; strip B = +16
  const int qB  = qA + 16;

  const size_t base = (size_t)bh * SS * DD;
  const short* kbase = Kbf + base;                         // [k][d] rows, tiles contiguous
  const short* vtb   = Vtp + (size_t)bh * 64 * 2048;       // [tile][d][32]

  // ---- stage first tile (coalesced lane-linear DMA, 2 insts/wave) ----
  {
    const short* gk = kbase + (size_t)kt0 * 2048 + w * 512 + lane * 8;
    gload16(gk, &Sh[0][w * 544]);
    const short* gv = vtb + (size_t)kt0 * 2048 + w * 512 + lane * 8;
    gload16(gv, &Sh[0][2176 + w * 512]);
  }

  // ---- Q fragments (B-operand layout), overlap with staging latency ----
  short8 qaA0, qaA1, qaB0, qaB1;
  {
    const float* ga = Q + base + (size_t)(qA + l16) * DD + quad * 8;
    const float* gb = Q + base + (size_t)(qB + l16) * DD + quad * 8;
    floatx4 a0 = *(const floatx4*)ga,        a1 = *(const floatx4*)(ga + 4);
    floatx4 a2 = *(const floatx4*)(ga + 32), a3 = *(const floatx4*)(ga + 36);
    floatx4 b0 = *(const floatx4*)gb,        b1 = *(const floatx4*)(gb + 4);
    floatx4 b2 = *(const floatx4*)(gb + 32), b3 = *(const floatx4*)(gb + 36);
    #pragma unroll
    for (int j = 0; j < 4; ++j) {
      qaA0[j] = f2bf(a0[j] * QSCALE); qaA0[4 + j] = f2bf(a1[j] * QSCALE);
      qaA1[j] = f2bf(a2[j] * QSCALE); qaA1[4 + j] = f2bf(a3[j] * QSCALE);
      qaB0[j] = f2bf(b0[j] * QSCALE); qaB0[4 + j] = f2bf(b1[j] * QSCALE);
      qaB1[j] = f2bf(b2[j] * QSCALE); qaB1[4 + j] = f2bf(b3[j] * QSCALE);
    }
  }

  floatx4 z = {0.f, 0.f, 0.f, 0.f};
  floatx4 oA0 = z, oA1 = z, oA2 = z, oA3 = z;   // O^T: q = l16, d = i*16+quad*4+r
  floatx4 oB0 = z, oB1 = z, oB2 = z, oB3 = z;
  float rsA = 0.f, rsB = 0.f;

  __asm__ volatile("s_waitcnt vmcnt(0)" ::: "memory");
  __syncthreads();

  int nb = 0;
  for (int kt = kt0; kt < kt1; ++kt) {
    // ---- issue next tile's DMA into the other buffer ----
    if (kt + 1 < kt1) {
      const short* gk = kbase + (size_t)(kt + 1) * 2048 + w * 512 + lane * 8;
      gload16(gk, &Sh[nb ^ 1][w * 544]);
      const short* gv = vtb + (size_t)(kt + 1) * 2048 + w * 512 + lane * 8;
      gload16(gv, &Sh[nb ^ 1][2176 + w * 512]);
    }

    if (kt <= ktd) {    // causal: skip tiles above this wave's diagonal
      const short* lb = Sh[nb];
      const int kro = (l16 & 7) * 64 + quad * 8;
      const int kc  = (l16 >> 3) * 544;
      short8 kb00 = *(const short8*)(lb + kc + kro);
      short8 kb01 = *(const short8*)(lb + kc + kro + 32);
      short8 kb10 = *(const short8*)(lb + kc + 1088 + kro);
      short8 kb11 = *(const short8*)(lb + kc + 1088 + kro + 32);
      const int vro = 2176 + l16 * 32 + quad * 8;
      short8 vt0 = *(const short8*)(lb + vro);
      short8 vt1 = *(const short8*)(lb + vro + 512);
      short8 vt2 = *(const short8*)(lb + vro + 1024);
      short8 vt3 = *(const short8*)(lb + vro + 1536);

      // ---- S^T = K Q^T ----
      floatx4 tA0 = z, tA1 = z, tB0 = z, tB1 = z;
      tA0 = MFMA(kb00, qaA0, tA0, 0, 0, 0); tA0 = MFMA(kb01, qaA1, tA0, 0, 0, 0);
      tA1 = MFMA(kb10, qaA0, tA1, 0, 0, 0); tA1 = MFMA(kb11, qaA1, tA1, 0, 0, 0);
      tB0 = MFMA(kb00, qaB0, tB0, 0, 0, 0); tB0 = MFMA(kb01, qaB1, tB0, 0, 0, 0);
      tB1 = MFMA(kb10, qaB0, tB1, 0, 0, 0); tB1 = MFMA(kb11, qaB1, tB1, 0, 0, 0);

      // ---- causal mask on the wave's own diagonal tile ----
      if (kt == ktd) {
        const int kq = quad * 4;
        #pragma unroll
        for (int r = 0; r < 4; ++r) {
          tA0[r] = (kq + r      <= l16)      ? tA0[r] : -1e30f;
          tA1[r] = (kq + r + 16 <= l16)      ? tA1[r] : -1e30f;
          tB0[r] = (kq + r      <= l16 + 16) ? tB0[r] : -1e30f;
          tB1[r] = (kq + r      <= l16)      ? tB1[r] : -1e30f;
        }
      }

      // ---- exp2, pack P into B-operand frags (registers only) ----
      short8 paA, paB;
      #pragma unroll
      for (int r = 0; r < 4; ++r) {
        const float pA0 = fexp2(tA0[r] - M_SUB), pA1 = fexp2(tA1[r] - M_SUB);
        const float pB0 = fexp2(tB0[r] - M_SUB), pB1 = fexp2(tB1[r] - M_SUB);
        rsA += pA0 + pA1;
        rsB += pB0 + pB1;
        paA[r] = f2bf_fast(pA0); paA[4 + r] = f2bf_fast(pA1);
        paB[r] = f2bf_fast(pB0); paB[4 + r] = f2bf_fast(pB1);
      }

      // ---- O^T += V^T P^T ----
      oA0 = MFMA(vt0, paA, oA0, 0, 0, 0); oA1 = MFMA(vt1, paA, oA1, 0, 0, 0);
      oA2 = MFMA(vt2, paA, oA2, 0, 0, 0); oA3 = MFMA(vt3, paA, oA3, 0, 0, 0);
      oB0 = MFMA(vt0, paB, oB0, 0, 0, 0); oB1 = MFMA(vt1, paB, oB1, 0, 0, 0);
      oB2 = MFMA(vt2, paB, oB2, 0, 0, 0); oB3 = MFMA(vt3, paB, oB3, 0, 0, 0);
    }

    __asm__ volatile("s_waitcnt vmcnt(0)" ::: "memory");  // own DMA done
    __syncthreads();                                       // everyone's DMA done
    nb ^= 1;
  }

  // ---- row sums: reduce across quads (q = l16 fixed) ----
  rsA += __shfl_xor(rsA, 16, 64); rsA += __shfl_xor(rsA, 32, 64);
  rsB += __shfl_xor(rsB, 16, 64); rsB += __shfl_xor(rsB, 32, 64);

  // ---- store unnormalized partials: PO[slot][128 rows][64 d] ----
  const int slot = bh * NCHUNK + y;
  float* po = PO + (size_t)slot * (128 * 64);
  float* ra = po + (w * 32 + l16) * 64 + quad * 4;
  float* rb = po + (w * 32 + 16 + l16) * 64 + quad * 4;
  *(floatx4*)(ra)      = oA0;
  *(floatx4*)(ra + 16) = oA1;
  *(floatx4*)(ra + 32) = oA2;
  *(floatx4*)(ra + 48) = oA3;
  *(floatx4*)(rb)      = oB0;
  *(floatx4*)(rb + 16) = oB1;
  *(floatx4*)(rb + 32) = oB2;
  *(floatx4*)(rb + 48) = oB3;
  if (quad == 0) {
    PRS[slot * 128 + w * 32 + l16]      = rsA;
    PRS[slot * 128 + w * 32 + 16 + l16] = rsB;
  }
}

// ---------- combine: sum partials, normalize, write O ----------
__global__ __launch_bounds__(256) void sdpa_combine(
    const float* __restrict__ PO, const float* __restrict__ PRS,
    float* __restrict__ O) {
  const int bh  = blockIdx.x;
  const int g32 = blockIdx.y;        // 0..63 (32-row groups)
  const int qt  = g32 >> 2;
  const int t   = threadIdx.x;
  const int row  = t >> 3;           // 0..31
  const int col  = (t & 7) * 8;
  const int rloc = (g32 & 3) * 32 + row;   // 0..127 within the q-tile

  const int g  = qt >> 2;
  const int cn = g + 1;
  int ybase;
  if      (g == 0) ybase = qt;
  else if (g == 1) ybase = 4 + 2 * (qt - 4);
  else if (g == 2) ybase = 12 + 3 * (qt - 8);
  else             ybase = 24 + 4 * (qt - 12);

  floatx4 accL = {0.f,0.f,0.f,0.f}, accH = accL;
  float den = 0.f;
  for (int c = 0; c < cn; ++c) {
    const int slot = bh * NCHUNK + ybase + c;
    const float* po = PO + (size_t)slot * (128 * 64) + rloc * 64 + col;
    floatx4 a = *(const floatx4*)po;
    floatx4 b = *(const floatx4*)(po + 4);
    accL += a; accH += b;
    den += PRS[slot * 128 + rloc];
  }
  const float inv = 1.0f / den;
  accL *= inv; accH *= inv;
  float* out = O + ((size_t)bh * SS + qt * 128 + rloc) * DD + col;
  *(floatx4*)out = accL;
  *(floatx4*)(out + 4) = accH;
}

extern "C" void kernel_launch(void* const* d_in, const int* in_sizes, int n_in,
                              void* d_out, int out_size, void* d_ws, size_t ws_size,
                              hipStream_t stream) {
  (void)in_sizes; (void)n_in; (void)out_size; (void)ws_size;
  const float* q = (const float*)d_in[0];
  const float* k = (const float*)d_in[1];
  const float* v = (const float*)d_in[2];
  float* o = (float*)d_out;

  short* Kbf = (short*)d_ws;                               // 8 MB
  short* Vtp = Kbf + (size_t)BH * SS * DD;                 // 8 MB
  float* PO  = (float*)(Vtp + (size_t)BH * SS * DD);       // 40 MB
  float* PRS = PO + (size_t)NSLOT * 128 * 64;              // 640 KB

  prep_k<<<dim3(BH * SS * DD / 8 / 256), 256, 0, stream>>>(k, Kbf);
  prep_vtp<<<dim3(SS / 64, BH), 256, 0, stream>>>(v, Vtp);
  sdpa_part<<<dim3(BH, NCHUNK), 256, 0, stream>>>(q, Kbf, Vtp, PO, PRS);
  sdpa_combine<<<dim3(BH, SS / 32), 256, 0, stream>>>(PO, PRS, o);
}